// Round 1
// baseline (1192.032 us; speedup 1.0000x reference)
//
#include <hip/hip_runtime.h>
#include <hip/hip_bf16.h>
#include <cstdint>
#include <cstddef>

typedef float f32x4 __attribute__((ext_vector_type(4)));
typedef __bf16 bf16x8v __attribute__((ext_vector_type(8)));

#define BM 128
#define BN 128
#define BK 32
#define LDSS 40   // LDS row stride (32 + 8 pad) -> 2-way bank aliasing only (free)

// ---------------- small kernels ----------------

__global__ void init_meta_kernel(int* __restrict__ map_s, int* __restrict__ map_t,
                                 int* __restrict__ cnt, float* __restrict__ iacc,
                                 float* __restrict__ cacc) {
  int i = blockIdx.x * 256 + threadIdx.x;   // grid = 128 blocks -> 0..32767
  map_s[i] = -1;
  map_t[i] = -1;
  if (i < 16) cnt[i] = 0;
  if (i < 8192) { iacc[i] = 0.f; cacc[i] = 0.f; }
}

__global__ void build_maps_kernel(const int* __restrict__ sics, int Ns,
                                  const int* __restrict__ tics, int Nt,
                                  int* __restrict__ map_s, int* __restrict__ map_t,
                                  int* __restrict__ cnt) {
  int j = blockIdx.x * 256 + threadIdx.x;
  if (j < Ns) { int p = sics[j]; map_s[p] = j; atomicAdd(&cnt[p >> 12], 1); }
  if (j < Nt) { int p = tics[j]; map_t[p] = j; atomicAdd(&cnt[8 + (p >> 12)], 1); }
}

__global__ void convert_pad_kernel(const float* __restrict__ src, int sld,
                                   __hip_bfloat16* __restrict__ dst, int total,
                                   int K, int Kpad) {
  int i = blockIdx.x * 256 + threadIdx.x;
  if (i >= total) return;
  int r = i / Kpad;
  int k = i - r * Kpad;
  dst[i] = __float2bfloat16(k < K ? src[(size_t)r * sld + k] : 0.f);
}

// ---------------- GEMM: C = relu(A @ W^T + bias-ish), bf16 MFMA ----------------
// A_F32: A operand is fp32 (converted to bf16 during LDS staging) else bf16.
// EPI: 0 = bias+relu -> store bf16 to outp (ldo)
//      1 = bias+relu -> per-batch column sums atomically added to red_acc[b*N+col]
//      2 = glob[b][col]+relu -> store bf16 (z = relu(X@Ws1_s^T + glob[b]))
// M must be a multiple of 128 (Ns=23552=184*128, Nt=24704=193*128).
template<int A_F32, int EPI>
__global__ __launch_bounds__(256, 2)
void gemm_kernel(const void* __restrict__ Aptr, int lda,
                 const __hip_bfloat16* __restrict__ Bw, int ldb,
                 const float* __restrict__ bias,
                 float* __restrict__ red_acc,
                 const float* __restrict__ globv,
                 const int* __restrict__ ridx,
                 __hip_bfloat16* __restrict__ outp, int ldo,
                 int M, int N, int Kreal, int Kpad)
{
  __shared__ alignas(16) __hip_bfloat16 lA[BM * LDSS];
  __shared__ alignas(16) __hip_bfloat16 lB[BN * LDSS];
  const int tid  = threadIdx.x;
  const int lane = tid & 63;
  const int wave = tid >> 6;
  const int quad = lane >> 4;
  const int l16  = lane & 15;
  const int wr   = wave >> 1;
  const int wc   = wave & 1;
  const int m0   = blockIdx.x * BM;
  const int n0   = blockIdx.y * BN;

  f32x4 acc[4][4];
  const f32x4 zero4 = {0.f, 0.f, 0.f, 0.f};
#pragma unroll
  for (int i = 0; i < 4; ++i)
#pragma unroll
    for (int j = 0; j < 4; ++j) acc[i][j] = zero4;

  for (int k0 = 0; k0 < Kpad; k0 += BK) {
    // ---- stage A tile (BM x BK) ----
#pragma unroll
    for (int it = 0; it < 2; ++it) {
      int g   = tid + it * 256;
      int row = g >> 2;
      int kg  = (g & 3) << 3;
      int ks  = k0 + kg;
      alignas(16) __hip_bfloat16 tmp[8];
      if (A_F32) {
        const float* src = (const float*)Aptr + (size_t)(m0 + row) * lda + ks;
        if (ks + 7 < Kreal) {
          float4 f0 = ((const float4*)src)[0];
          float4 f1 = ((const float4*)src)[1];
          tmp[0] = __float2bfloat16(f0.x); tmp[1] = __float2bfloat16(f0.y);
          tmp[2] = __float2bfloat16(f0.z); tmp[3] = __float2bfloat16(f0.w);
          tmp[4] = __float2bfloat16(f1.x); tmp[5] = __float2bfloat16(f1.y);
          tmp[6] = __float2bfloat16(f1.z); tmp[7] = __float2bfloat16(f1.w);
        } else {
#pragma unroll
          for (int i = 0; i < 8; ++i)
            tmp[i] = __float2bfloat16((ks + i < Kreal) ? src[i] : 0.f);
        }
      } else {
        const __hip_bfloat16* src = (const __hip_bfloat16*)Aptr + (size_t)(m0 + row) * lda + ks;
        if (ks + 7 < Kreal) {
          *(uint4*)tmp = *(const uint4*)src;
        } else {
#pragma unroll
          for (int i = 0; i < 8; ++i)
            tmp[i] = (ks + i < Kreal) ? src[i] : __float2bfloat16(0.f);
        }
      }
      *(uint4*)&lA[row * LDSS + kg] = *(uint4*)tmp;
    }
    // ---- stage B tile (BN x BK) from pre-padded bf16 weights ----
#pragma unroll
    for (int it = 0; it < 2; ++it) {
      int g   = tid + it * 256;
      int row = g >> 2;
      int kg  = (g & 3) << 3;
      uint4 pack = {0u, 0u, 0u, 0u};
      if (n0 + row < N)
        pack = *(const uint4*)(Bw + (size_t)(n0 + row) * ldb + k0 + kg);
      *(uint4*)&lB[row * LDSS + kg] = pack;
    }
    __syncthreads();
    bf16x8v af[4], bfr[4];
#pragma unroll
    for (int i = 0; i < 4; ++i) {
      af[i]  = *(const bf16x8v*)&lA[(wr * 64 + i * 16 + l16) * LDSS + quad * 8];
      bfr[i] = *(const bf16x8v*)&lB[(wc * 64 + i * 16 + l16) * LDSS + quad * 8];
    }
#pragma unroll
    for (int mi = 0; mi < 4; ++mi)
#pragma unroll
      for (int ni = 0; ni < 4; ++ni)
        acc[mi][ni] = __builtin_amdgcn_mfma_f32_16x16x32_bf16(af[mi], bfr[ni], acc[mi][ni], 0, 0, 0);
    __syncthreads();
  }

  if (EPI == 1) {
    // masked per-batch column sums. Rows are batch-sorted; a 128-row tile spans
    // at most 2 batches (min batch len 2048).
    const int b0 = ridx[m0] >> 12;
#pragma unroll
    for (int ni = 0; ni < 4; ++ni) {
      const int col = n0 + wc * 64 + ni * 16 + l16;
      const bool colok = col < N;
      const float bcol = colok ? bias[col] : 0.f;
#pragma unroll
      for (int mi = 0; mi < 4; ++mi) {
        float v0 = 0.f, v1 = 0.f;
#pragma unroll
        for (int r = 0; r < 4; ++r) {
          const int row = m0 + wr * 64 + mi * 16 + quad * 4 + r;
          const float v = fmaxf(acc[mi][ni][r] + bcol, 0.f);
          const int b = ridx[row] >> 12;
          if (b == b0) v0 += v; else v1 += v;
        }
        v0 += __shfl_xor(v0, 16, 64); v0 += __shfl_xor(v0, 32, 64);
        v1 += __shfl_xor(v1, 16, 64); v1 += __shfl_xor(v1, 32, 64);
        if (quad == 0 && colok) {
          atomicAdd(&red_acc[b0 * N + col], v0);
          if (b0 + 1 < 8 && v1 != 0.f) atomicAdd(&red_acc[(b0 + 1) * N + col], v1);
        }
      }
    }
  } else {
#pragma unroll
    for (int mi = 0; mi < 4; ++mi) {
#pragma unroll
      for (int r = 0; r < 4; ++r) {
        const int row = m0 + wr * 64 + mi * 16 + quad * 4 + r;
        int b = 0;
        if (EPI == 2) b = ridx[row] >> 12;
#pragma unroll
        for (int ni = 0; ni < 4; ++ni) {
          const int col = n0 + wc * 64 + ni * 16 + l16;
          if (col < N) {
            float v = acc[mi][ni][r];
            v += (EPI == 2) ? globv[b * N + col] : bias[col];
            v = fmaxf(v, 0.f);
            outp[(size_t)row * ldo + col] = __float2bfloat16(v);
          }
        }
      }
    }
  }
}

// glob[b][o] = bs1[o] + (inst_acc[b]/cnt_s[b]) . Ws1[o,528:1552] + (cat_acc[b]/cnt_t[b]) . Ws1[o,1552:2576]
__global__ __launch_bounds__(256) void glob_kernel(const float* __restrict__ iacc,
                                                   const float* __restrict__ cacc,
                                                   const int* __restrict__ cnt,
                                                   const float* __restrict__ Ws1,
                                                   const float* __restrict__ bs1,
                                                   float* __restrict__ globv) {
  int w    = (blockIdx.x * 256 + threadIdx.x) >> 6;  // 4096 waves
  int lane = threadIdx.x & 63;
  int b = w >> 9;
  int o = w & 511;
  const float* wi = Ws1 + (size_t)o * 2576 + 528;
  const float* wcp = Ws1 + (size_t)o * 2576 + 1552;
  float a1 = 0.f, a2 = 0.f;
  for (int k = lane; k < 1024; k += 64) {
    a1 += iacc[b * 1024 + k] * wi[k];
    a2 += cacc[b * 1024 + k] * wcp[k];
  }
  for (int off = 32; off; off >>= 1) {
    a1 += __shfl_xor(a1, off, 64);
    a2 += __shfl_xor(a2, off, 64);
  }
  if (lane == 0)
    globv[b * 512 + o] = bs1[o] + a1 / (float)cnt[b] + a2 / (float)cnt[8 + b];
}

// s value for an all-zero (invalid) row of batch b, full fp32 path
__global__ __launch_bounds__(256) void s_empty_kernel(const float* __restrict__ globv,
                                                      const float* __restrict__ Ws2,
                                                      const float* __restrict__ bs2,
                                                      const float* __restrict__ Ws3,
                                                      const float* __restrict__ bs3,
                                                      float* __restrict__ semp) {
  __shared__ float zrow[512];
  __shared__ float wsum[4];
  int b = blockIdx.x, t = threadIdx.x;
  zrow[t]       = fmaxf(globv[b * 512 + t], 0.f);
  zrow[t + 256] = fmaxf(globv[b * 512 + t + 256], 0.f);
  __syncthreads();
  float acc = bs2[t];
  for (int o = 0; o < 512; ++o) acc += zrow[o] * Ws2[t * 512 + o];
  float p = fmaxf(acc, 0.f) * Ws3[t];
  for (int off = 32; off; off >>= 1) p += __shfl_xor(p, off, 64);
  if ((t & 63) == 0) wsum[t >> 6] = p;
  __syncthreads();
  if (t == 0) semp[b] = wsum[0] + wsum[1] + wsum[2] + wsum[3] + bs3[0];
}

// s[row] = z2[row] . Ws3 + bs3 (one wave per row)
__global__ __launch_bounds__(256) void s_dot_kernel(const __hip_bfloat16* __restrict__ z2,
                                                    const float* __restrict__ Ws3,
                                                    const float* __restrict__ bs3,
                                                    float* __restrict__ sbuf, int M) {
  int w = (blockIdx.x * 256 + threadIdx.x) >> 6;
  int lane = threadIdx.x & 63;
  if (w >= M) return;
  const __hip_bfloat16* zr = z2 + (size_t)w * 256;
  float a = 0.f;
  for (int k = lane; k < 256; k += 64) a += __bfloat162float(zr[k]) * Ws3[k];
  for (int off = 32; off; off >>= 1) a += __shfl_xor(a, off, 64);
  if (lane == 0) sbuf[w] = a + bs3[0];
}

// outputs 0/1: scattered geo * inv (zeros where invalid); one block per row
__global__ __launch_bounds__(256) void fill_feats_kernel(const float* __restrict__ geo,
                                                         const int* __restrict__ map_s,
                                                         const int* __restrict__ map_t,
                                                         float* __restrict__ out0,
                                                         float* __restrict__ out1,
                                                         int Ns, float inv) {
  int bid = blockIdx.x;              // 0..65535
  bool is_t = bid >= 32768;
  int pos = is_t ? bid - 32768 : bid;
  int j = is_t ? map_t[pos] : map_s[pos];
  float* outp = (is_t ? out1 : out0) + (size_t)pos * 528;
  if (j >= 0) {
    const float* g = geo + (size_t)(is_t ? Ns + j : j) * 528;
    for (int d = threadIdx.x; d < 528; d += 256) outp[d] = g[d] * inv;
  } else {
    for (int d = threadIdx.x; d < 528; d += 256) outp[d] = 0.f;
  }
}

__global__ void fill_pcd_kernel(const float* __restrict__ pcd,
                                const int* __restrict__ map_s,
                                const int* __restrict__ map_t,
                                float* __restrict__ out2, float* __restrict__ out3,
                                int Ns) {
  int i = blockIdx.x * 256 + threadIdx.x;   // 0..65535
  if (i >= 65536) return;
  bool is_t = i >= 32768;
  int pos = is_t ? i - 32768 : i;
  int j = is_t ? map_t[pos] : map_s[pos];
  float* o = (is_t ? out3 : out2) + (size_t)pos * 3;
  if (j >= 0) {
    const float* p = pcd + (size_t)(is_t ? Ns + j : j) * 3;
    o[0] = p[0]; o[1] = p[1]; o[2] = p[2];
  } else {
    o[0] = 0.f; o[1] = 0.f; o[2] = 0.f;
  }
}

__global__ void scale_kernel(const float* __restrict__ sbuf,
                             const float* __restrict__ semp,
                             const int* __restrict__ map_s,
                             float* __restrict__ out4) {
  int i = blockIdx.x * 256 + threadIdx.x;   // 0..32767
  if (i >= 32768) return;
  int j = map_s[i];
  float s = (j >= 0) ? sbuf[j] : semp[i >> 12];
  out4[i] = 1.f / (1.f + expf(-s)) - 0.5f;
}

// ---------------- host ----------------

extern "C" void kernel_launch(void* const* d_in, const int* in_sizes, int n_in,
                              void* d_out, int out_size, void* d_ws, size_t ws_size,
                              hipStream_t stream) {
  const float* geo = (const float*)d_in[0];
  const float* pcd = (const float*)d_in[1];
  const float* Wi1 = (const float*)d_in[2];
  const float* bi1 = (const float*)d_in[3];
  const float* Wi2 = (const float*)d_in[4];
  const float* bi2 = (const float*)d_in[5];
  const float* Wc1 = (const float*)d_in[6];
  const float* bc1 = (const float*)d_in[7];
  const float* Wc2 = (const float*)d_in[8];
  const float* bc2 = (const float*)d_in[9];
  const float* Ws1 = (const float*)d_in[10];
  const float* bs1 = (const float*)d_in[11];
  const float* Ws2 = (const float*)d_in[12];
  const float* bs2 = (const float*)d_in[13];
  const float* Ws3 = (const float*)d_in[14];
  const float* bs3 = (const float*)d_in[15];
  const int* sics = (const int*)d_in[18];
  const int* tics = (const int*)d_in[19];
  const int Ns = in_sizes[18];   // 23552 = 184*128
  const int Nt = in_sizes[19];   // 24704 = 193*128
  const int D = 528;

  float* out0 = (float*)d_out;                      // (8,4096,528)
  float* out1 = out0 + (size_t)8 * 4096 * 528;      // (8,4096,528)
  float* out2 = out1 + (size_t)8 * 4096 * 528;      // (8,4096,3)
  float* out3 = out2 + (size_t)8 * 4096 * 3;        // (8,4096,3)
  float* out4 = out3 + (size_t)8 * 4096 * 3;        // (8,1,4096)

  char* wp = (char*)d_ws;
  auto alloc = [&](size_t bytes) -> void* {
    void* p = (void*)wp;
    wp += (bytes + 255) & ~(size_t)255;
    return p;
  };
  int*   map_s = (int*)  alloc((size_t)32768 * 4);
  int*   map_t = (int*)  alloc((size_t)32768 * 4);
  int*   cnt   = (int*)  alloc(64);
  float* iacc  = (float*)alloc((size_t)8 * 1024 * 4);
  float* cacc  = (float*)alloc((size_t)8 * 1024 * 4);
  float* globb = (float*)alloc((size_t)8 * 512 * 4);
  float* semp  = (float*)alloc(64);
  float* sbuf  = (float*)alloc((size_t)Ns * 4);
  __hip_bfloat16* Wi1b  = (__hip_bfloat16*)alloc((size_t)528  * 544 * 2);
  __hip_bfloat16* Wi2b  = (__hip_bfloat16*)alloc((size_t)1024 * 544 * 2);
  __hip_bfloat16* Wc1b  = (__hip_bfloat16*)alloc((size_t)528  * 544 * 2);
  __hip_bfloat16* Wc2b  = (__hip_bfloat16*)alloc((size_t)1024 * 544 * 2);
  __hip_bfloat16* Ws1sb = (__hip_bfloat16*)alloc((size_t)512  * 544 * 2);
  __hip_bfloat16* Ws2b  = (__hip_bfloat16*)alloc((size_t)256  * 512 * 2);
  __hip_bfloat16* big   = (__hip_bfloat16*)alloc((size_t)Nt * 544 * 2);  // h1 / g1 / z
  __hip_bfloat16* z2b   = (__hip_bfloat16*)alloc((size_t)Ns * 256 * 2);

  init_meta_kernel<<<dim3(128), dim3(256), 0, stream>>>(map_s, map_t, cnt, iacc, cacc);
  {
    int n = Ns > Nt ? Ns : Nt;
    build_maps_kernel<<<dim3((n + 255) / 256), dim3(256), 0, stream>>>(
        sics, Ns, tics, Nt, map_s, map_t, cnt);
  }
  auto conv = [&](const float* src, int sld, __hip_bfloat16* dst, int rows, int K, int Kpad) {
    int total = rows * Kpad;
    convert_pad_kernel<<<dim3((total + 255) / 256), dim3(256), 0, stream>>>(
        src, sld, dst, total, K, Kpad);
  };
  conv(Wi1, 528,  Wi1b,  528,  528, 544);
  conv(Wi2, 528,  Wi2b,  1024, 528, 544);
  conv(Wc1, 528,  Wc1b,  528,  528, 544);
  conv(Wc2, 528,  Wc2b,  1024, 528, 544);
  conv(Ws1, 2576, Ws1sb, 512,  528, 544);
  conv(Ws2, 512,  Ws2b,  256,  512, 512);

  // GEMM1: h1 = relu(geo_src @ Wi1^T + bi1) -> big (ld 544)
  gemm_kernel<1, 0><<<dim3(Ns / 128, 5), dim3(256), 0, stream>>>(
      geo, D, Wi1b, 544, bi1, nullptr, nullptr, nullptr, big, 544, Ns, 528, 528, 544);
  // GEMM2: inst_acc[b] += sum relu(h1 @ Wi2^T + bi2)
  gemm_kernel<0, 1><<<dim3(Ns / 128, 8), dim3(256), 0, stream>>>(
      big, 544, Wi2b, 544, bi2, iacc, nullptr, sics, nullptr, 0, Ns, 1024, 528, 544);
  // GEMM3: g1 = relu(geo_tgt @ Wc1^T + bc1) -> big
  gemm_kernel<1, 0><<<dim3(Nt / 128, 5), dim3(256), 0, stream>>>(
      geo + (size_t)Ns * D, D, Wc1b, 544, bc1, nullptr, nullptr, nullptr, big, 544, Nt, 528, 528, 544);
  // GEMM4: cat_acc[b] += sum relu(g1 @ Wc2^T + bc2)
  gemm_kernel<0, 1><<<dim3(Nt / 128, 8), dim3(256), 0, stream>>>(
      big, 544, Wc2b, 544, bc2, cacc, nullptr, tics, nullptr, 0, Nt, 1024, 528, 544);

  glob_kernel<<<dim3(1024), dim3(256), 0, stream>>>(iacc, cacc, cnt, Ws1, bs1, globb);
  s_empty_kernel<<<dim3(8), dim3(256), 0, stream>>>(globb, Ws2, bs2, Ws3, bs3, semp);

  // GEMM5: z = relu(geo_src @ Ws1_s^T + glob[b]) -> big (ld 512)
  gemm_kernel<1, 2><<<dim3(Ns / 128, 4), dim3(256), 0, stream>>>(
      geo, D, Ws1sb, 544, nullptr, nullptr, globb, sics, big, 512, Ns, 512, 528, 544);
  // GEMM6: z2 = relu(z @ Ws2^T + bs2) -> z2b (ld 256)
  gemm_kernel<0, 0><<<dim3(Ns / 128, 2), dim3(256), 0, stream>>>(
      big, 512, Ws2b, 512, bs2, nullptr, nullptr, nullptr, z2b, 256, Ns, 256, 512, 512);

  s_dot_kernel<<<dim3((Ns + 3) / 4), dim3(256), 0, stream>>>(z2b, Ws3, bs3, sbuf, Ns);

  float inv = 1.0f / sqrtf(528.0f);
  fill_feats_kernel<<<dim3(65536), dim3(256), 0, stream>>>(geo, map_s, map_t, out0, out1, Ns, inv);
  fill_pcd_kernel<<<dim3(256), dim3(256), 0, stream>>>(pcd, map_s, map_t, out2, out3, Ns);
  scale_kernel<<<dim3(128), dim3(256), 0, stream>>>(sbuf, semp, map_s, out4);
}

// Round 2
// 643.413 us; speedup vs baseline: 1.8527x; 1.8527x over previous
//
#include <hip/hip_runtime.h>
#include <hip/hip_bf16.h>
#include <cstdint>
#include <cstddef>

typedef float f32x4 __attribute__((ext_vector_type(4)));
typedef __bf16 bf16x8v __attribute__((ext_vector_type(8)));

#define BM 128
#define BN 128
#define BK 32
#define LDSS 40   // LDS row stride (32 + 8 pad) -> 2-way bank aliasing only (free)

// ---------------- small kernels ----------------
// cnt layout: cnt[0..8] = src batch start offsets (cnt[8]=Ns), cnt[9..17] = tgt starts (cnt[17]=Nt)

__global__ void init_meta_kernel(int* __restrict__ map_s, int* __restrict__ map_t,
                                 int* __restrict__ cnt, float* __restrict__ iacc,
                                 float* __restrict__ cacc, int Ns, int Nt) {
  int i = blockIdx.x * 256 + threadIdx.x;   // grid = 128 blocks -> 0..32767
  map_s[i] = -1;
  map_t[i] = -1;
  if (i == 0) { cnt[8] = Ns; cnt[17] = Nt; }
  if (i < 8192) { iacc[i] = 0.f; cacc[i] = 0.f; }
}

// atomic-free: batch boundaries detected by comparing adjacent sorted indices
__global__ void build_maps_kernel(const int* __restrict__ sics, int Ns,
                                  const int* __restrict__ tics, int Nt,
                                  int* __restrict__ map_s, int* __restrict__ map_t,
                                  int* __restrict__ cnt) {
  int j = blockIdx.x * 256 + threadIdx.x;
  if (j < Ns) {
    int p = sics[j];
    map_s[p] = j;
    int b = p >> 12;
    if (j == 0) cnt[0] = 0;
    else if ((sics[j - 1] >> 12) != b) cnt[b] = j;
  }
  if (j < Nt) {
    int p = tics[j];
    map_t[p] = j;
    int b = p >> 12;
    if (j == 0) cnt[9] = 0;
    else if ((tics[j - 1] >> 12) != b) cnt[9 + b] = j;
  }
}

__global__ void convert_pad_kernel(const float* __restrict__ src, int sld,
                                   __hip_bfloat16* __restrict__ dst, int total,
                                   int K, int Kpad) {
  int i = blockIdx.x * 256 + threadIdx.x;
  if (i >= total) return;
  int r = i / Kpad;
  int k = i - r * Kpad;
  dst[i] = __float2bfloat16(k < K ? src[(size_t)r * sld + k] : 0.f);
}

// ---------------- GEMM: C = relu(A @ W^T + bias-ish), bf16 MFMA ----------------
// A_F32: A operand is fp32 (converted to bf16 during LDS staging) else bf16.
// EPI: 0 = bias+relu -> store bf16 to outp (ldo)
//      1 = bias+relu -> per-batch column sums atomically added to red_acc[b*N+col]
//      2 = glob[b][col]+relu -> store bf16 (z = relu(X@Ws1_s^T + glob[b]))
// M must be a multiple of 128 (Ns=23552=184*128, Nt=24704=193*128).
template<int A_F32, int EPI>
__global__ __launch_bounds__(256, 2)
void gemm_kernel(const void* __restrict__ Aptr, int lda,
                 const __hip_bfloat16* __restrict__ Bw, int ldb,
                 const float* __restrict__ bias,
                 float* __restrict__ red_acc,
                 const float* __restrict__ globv,
                 const int* __restrict__ ridx,
                 __hip_bfloat16* __restrict__ outp, int ldo,
                 int M, int N, int Kreal, int Kpad)
{
  __shared__ alignas(16) __hip_bfloat16 lA[BM * LDSS];
  __shared__ alignas(16) __hip_bfloat16 lB[BN * LDSS];
  const int tid  = threadIdx.x;
  const int lane = tid & 63;
  const int wave = tid >> 6;
  const int quad = lane >> 4;
  const int l16  = lane & 15;
  const int wr   = wave >> 1;
  const int wc   = wave & 1;
  const int m0   = blockIdx.x * BM;
  const int n0   = blockIdx.y * BN;

  f32x4 acc[4][4];
  const f32x4 zero4 = {0.f, 0.f, 0.f, 0.f};
#pragma unroll
  for (int i = 0; i < 4; ++i)
#pragma unroll
    for (int j = 0; j < 4; ++j) acc[i][j] = zero4;

  for (int k0 = 0; k0 < Kpad; k0 += BK) {
    // ---- stage A tile (BM x BK) ----
#pragma unroll
    for (int it = 0; it < 2; ++it) {
      int g   = tid + it * 256;
      int row = g >> 2;
      int kg  = (g & 3) << 3;
      int ks  = k0 + kg;
      alignas(16) __hip_bfloat16 tmp[8];
      if (A_F32) {
        const float* src = (const float*)Aptr + (size_t)(m0 + row) * lda + ks;
        if (ks + 7 < Kreal) {
          float4 f0 = ((const float4*)src)[0];
          float4 f1 = ((const float4*)src)[1];
          tmp[0] = __float2bfloat16(f0.x); tmp[1] = __float2bfloat16(f0.y);
          tmp[2] = __float2bfloat16(f0.z); tmp[3] = __float2bfloat16(f0.w);
          tmp[4] = __float2bfloat16(f1.x); tmp[5] = __float2bfloat16(f1.y);
          tmp[6] = __float2bfloat16(f1.z); tmp[7] = __float2bfloat16(f1.w);
        } else {
#pragma unroll
          for (int i = 0; i < 8; ++i)
            tmp[i] = __float2bfloat16((ks + i < Kreal) ? src[i] : 0.f);
        }
      } else {
        const __hip_bfloat16* src = (const __hip_bfloat16*)Aptr + (size_t)(m0 + row) * lda + ks;
        if (ks + 7 < Kreal) {
          *(uint4*)tmp = *(const uint4*)src;
        } else {
#pragma unroll
          for (int i = 0; i < 8; ++i)
            tmp[i] = (ks + i < Kreal) ? src[i] : __float2bfloat16(0.f);
        }
      }
      *(uint4*)&lA[row * LDSS + kg] = *(uint4*)tmp;
    }
    // ---- stage B tile (BN x BK) from pre-padded bf16 weights ----
#pragma unroll
    for (int it = 0; it < 2; ++it) {
      int g   = tid + it * 256;
      int row = g >> 2;
      int kg  = (g & 3) << 3;
      uint4 pack = {0u, 0u, 0u, 0u};
      if (n0 + row < N)
        pack = *(const uint4*)(Bw + (size_t)(n0 + row) * ldb + k0 + kg);
      *(uint4*)&lB[row * LDSS + kg] = pack;
    }
    __syncthreads();
    bf16x8v af[4], bfr[4];
#pragma unroll
    for (int i = 0; i < 4; ++i) {
      af[i]  = *(const bf16x8v*)&lA[(wr * 64 + i * 16 + l16) * LDSS + quad * 8];
      bfr[i] = *(const bf16x8v*)&lB[(wc * 64 + i * 16 + l16) * LDSS + quad * 8];
    }
#pragma unroll
    for (int mi = 0; mi < 4; ++mi)
#pragma unroll
      for (int ni = 0; ni < 4; ++ni)
        acc[mi][ni] = __builtin_amdgcn_mfma_f32_16x16x32_bf16(af[mi], bfr[ni], acc[mi][ni], 0, 0, 0);
    __syncthreads();
  }

  if (EPI == 1) {
    // masked per-batch column sums. Rows are batch-sorted; a 128-row tile spans
    // at most 2 batches (min batch len 2048).
    const int b0 = ridx[m0] >> 12;
#pragma unroll
    for (int ni = 0; ni < 4; ++ni) {
      const int col = n0 + wc * 64 + ni * 16 + l16;
      const bool colok = col < N;
      const float bcol = colok ? bias[col] : 0.f;
#pragma unroll
      for (int mi = 0; mi < 4; ++mi) {
        float v0 = 0.f, v1 = 0.f;
#pragma unroll
        for (int r = 0; r < 4; ++r) {
          const int row = m0 + wr * 64 + mi * 16 + quad * 4 + r;
          const float v = fmaxf(acc[mi][ni][r] + bcol, 0.f);
          const int b = ridx[row] >> 12;
          if (b == b0) v0 += v; else v1 += v;
        }
        v0 += __shfl_xor(v0, 16, 64); v0 += __shfl_xor(v0, 32, 64);
        v1 += __shfl_xor(v1, 16, 64); v1 += __shfl_xor(v1, 32, 64);
        if (quad == 0 && colok) {
          atomicAdd(&red_acc[b0 * N + col], v0);
          if (b0 + 1 < 8 && v1 != 0.f) atomicAdd(&red_acc[(b0 + 1) * N + col], v1);
        }
      }
    }
  } else {
#pragma unroll
    for (int mi = 0; mi < 4; ++mi) {
#pragma unroll
      for (int r = 0; r < 4; ++r) {
        const int row = m0 + wr * 64 + mi * 16 + quad * 4 + r;
        int b = 0;
        if (EPI == 2) b = ridx[row] >> 12;
#pragma unroll
        for (int ni = 0; ni < 4; ++ni) {
          const int col = n0 + wc * 64 + ni * 16 + l16;
          if (col < N) {
            float v = acc[mi][ni][r];
            v += (EPI == 2) ? globv[b * N + col] : bias[col];
            v = fmaxf(v, 0.f);
            outp[(size_t)row * ldo + col] = __float2bfloat16(v);
          }
        }
      }
    }
  }
}

// glob[b][o] = bs1[o] + (inst_acc[b]/cnt_s[b]) . Ws1[o,528:1552] + (cat_acc[b]/cnt_t[b]) . Ws1[o,1552:2576]
__global__ __launch_bounds__(256) void glob_kernel(const float* __restrict__ iacc,
                                                   const float* __restrict__ cacc,
                                                   const int* __restrict__ cnt,
                                                   const float* __restrict__ Ws1,
                                                   const float* __restrict__ bs1,
                                                   float* __restrict__ globv) {
  int w    = (blockIdx.x * 256 + threadIdx.x) >> 6;  // 4096 waves
  int lane = threadIdx.x & 63;
  int b = w >> 9;
  int o = w & 511;
  const float* wi = Ws1 + (size_t)o * 2576 + 528;
  const float* wcp = Ws1 + (size_t)o * 2576 + 1552;
  float a1 = 0.f, a2 = 0.f;
  for (int k = lane; k < 1024; k += 64) {
    a1 += iacc[b * 1024 + k] * wi[k];
    a2 += cacc[b * 1024 + k] * wcp[k];
  }
  for (int off = 32; off; off >>= 1) {
    a1 += __shfl_xor(a1, off, 64);
    a2 += __shfl_xor(a2, off, 64);
  }
  if (lane == 0) {
    float ns = (float)(cnt[b + 1] - cnt[b]);
    float nt = (float)(cnt[9 + b + 1] - cnt[9 + b]);
    globv[b * 512 + o] = bs1[o] + a1 / ns + a2 / nt;
  }
}

// s value for an all-zero (invalid) row of batch b, full fp32 path
__global__ __launch_bounds__(256) void s_empty_kernel(const float* __restrict__ globv,
                                                      const float* __restrict__ Ws2,
                                                      const float* __restrict__ bs2,
                                                      const float* __restrict__ Ws3,
                                                      const float* __restrict__ bs3,
                                                      float* __restrict__ semp) {
  __shared__ float zrow[512];
  __shared__ float wsum[4];
  int b = blockIdx.x, t = threadIdx.x;
  zrow[t]       = fmaxf(globv[b * 512 + t], 0.f);
  zrow[t + 256] = fmaxf(globv[b * 512 + t + 256], 0.f);
  __syncthreads();
  float acc = bs2[t];
  for (int o = 0; o < 512; ++o) acc += zrow[o] * Ws2[t * 512 + o];
  float p = fmaxf(acc, 0.f) * Ws3[t];
  for (int off = 32; off; off >>= 1) p += __shfl_xor(p, off, 64);
  if ((t & 63) == 0) wsum[t >> 6] = p;
  __syncthreads();
  if (t == 0) semp[b] = wsum[0] + wsum[1] + wsum[2] + wsum[3] + bs3[0];
}

// s[row] = z2[row] . Ws3 + bs3 (one wave per row)
__global__ __launch_bounds__(256) void s_dot_kernel(const __hip_bfloat16* __restrict__ z2,
                                                    const float* __restrict__ Ws3,
                                                    const float* __restrict__ bs3,
                                                    float* __restrict__ sbuf, int M) {
  int w = (blockIdx.x * 256 + threadIdx.x) >> 6;
  int lane = threadIdx.x & 63;
  if (w >= M) return;
  const __hip_bfloat16* zr = z2 + (size_t)w * 256;
  float a = 0.f;
  for (int k = lane; k < 256; k += 64) a += __bfloat162float(zr[k]) * Ws3[k];
  for (int off = 32; off; off >>= 1) a += __shfl_xor(a, off, 64);
  if (lane == 0) sbuf[w] = a + bs3[0];
}

// outputs 0/1: scattered geo * inv (zeros where invalid); one block per row
__global__ __launch_bounds__(256) void fill_feats_kernel(const float* __restrict__ geo,
                                                         const int* __restrict__ map_s,
                                                         const int* __restrict__ map_t,
                                                         float* __restrict__ out0,
                                                         float* __restrict__ out1,
                                                         int Ns, float inv) {
  int bid = blockIdx.x;              // 0..65535
  bool is_t = bid >= 32768;
  int pos = is_t ? bid - 32768 : bid;
  int j = is_t ? map_t[pos] : map_s[pos];
  float* outp = (is_t ? out1 : out0) + (size_t)pos * 528;
  if (j >= 0) {
    const float* g = geo + (size_t)(is_t ? Ns + j : j) * 528;
    for (int d = threadIdx.x; d < 528; d += 256) outp[d] = g[d] * inv;
  } else {
    for (int d = threadIdx.x; d < 528; d += 256) outp[d] = 0.f;
  }
}

__global__ void fill_pcd_kernel(const float* __restrict__ pcd,
                                const int* __restrict__ map_s,
                                const int* __restrict__ map_t,
                                float* __restrict__ out2, float* __restrict__ out3,
                                int Ns) {
  int i = blockIdx.x * 256 + threadIdx.x;   // 0..65535
  if (i >= 65536) return;
  bool is_t = i >= 32768;
  int pos = is_t ? i - 32768 : i;
  int j = is_t ? map_t[pos] : map_s[pos];
  float* o = (is_t ? out3 : out2) + (size_t)pos * 3;
  if (j >= 0) {
    const float* p = pcd + (size_t)(is_t ? Ns + j : j) * 3;
    o[0] = p[0]; o[1] = p[1]; o[2] = p[2];
  } else {
    o[0] = 0.f; o[1] = 0.f; o[2] = 0.f;
  }
}

__global__ void scale_kernel(const float* __restrict__ sbuf,
                             const float* __restrict__ semp,
                             const int* __restrict__ map_s,
                             float* __restrict__ out4) {
  int i = blockIdx.x * 256 + threadIdx.x;   // 0..32767
  if (i >= 32768) return;
  int j = map_s[i];
  float s = (j >= 0) ? sbuf[j] : semp[i >> 12];
  out4[i] = 1.f / (1.f + expf(-s)) - 0.5f;
}

// ---------------- host ----------------

extern "C" void kernel_launch(void* const* d_in, const int* in_sizes, int n_in,
                              void* d_out, int out_size, void* d_ws, size_t ws_size,
                              hipStream_t stream) {
  const float* geo = (const float*)d_in[0];
  const float* pcd = (const float*)d_in[1];
  const float* Wi1 = (const float*)d_in[2];
  const float* bi1 = (const float*)d_in[3];
  const float* Wi2 = (const float*)d_in[4];
  const float* bi2 = (const float*)d_in[5];
  const float* Wc1 = (const float*)d_in[6];
  const float* bc1 = (const float*)d_in[7];
  const float* Wc2 = (const float*)d_in[8];
  const float* bc2 = (const float*)d_in[9];
  const float* Ws1 = (const float*)d_in[10];
  const float* bs1 = (const float*)d_in[11];
  const float* Ws2 = (const float*)d_in[12];
  const float* bs2 = (const float*)d_in[13];
  const float* Ws3 = (const float*)d_in[14];
  const float* bs3 = (const float*)d_in[15];
  const int* sics = (const int*)d_in[18];
  const int* tics = (const int*)d_in[19];
  const int Ns = in_sizes[18];   // 23552 = 184*128
  const int Nt = in_sizes[19];   // 24704 = 193*128
  const int D = 528;

  float* out0 = (float*)d_out;                      // (8,4096,528)
  float* out1 = out0 + (size_t)8 * 4096 * 528;      // (8,4096,528)
  float* out2 = out1 + (size_t)8 * 4096 * 528;      // (8,4096,3)
  float* out3 = out2 + (size_t)8 * 4096 * 3;        // (8,4096,3)
  float* out4 = out3 + (size_t)8 * 4096 * 3;        // (8,1,4096)

  char* wp = (char*)d_ws;
  auto alloc = [&](size_t bytes) -> void* {
    void* p = (void*)wp;
    wp += (bytes + 255) & ~(size_t)255;
    return p;
  };
  int*   map_s = (int*)  alloc((size_t)32768 * 4);
  int*   map_t = (int*)  alloc((size_t)32768 * 4);
  int*   cnt   = (int*)  alloc(128);
  float* iacc  = (float*)alloc((size_t)8 * 1024 * 4);
  float* cacc  = (float*)alloc((size_t)8 * 1024 * 4);
  float* globb = (float*)alloc((size_t)8 * 512 * 4);
  float* semp  = (float*)alloc(64);
  float* sbuf  = (float*)alloc((size_t)Ns * 4);
  __hip_bfloat16* Wi1b  = (__hip_bfloat16*)alloc((size_t)528  * 544 * 2);
  __hip_bfloat16* Wi2b  = (__hip_bfloat16*)alloc((size_t)1024 * 544 * 2);
  __hip_bfloat16* Wc1b  = (__hip_bfloat16*)alloc((size_t)528  * 544 * 2);
  __hip_bfloat16* Wc2b  = (__hip_bfloat16*)alloc((size_t)1024 * 544 * 2);
  __hip_bfloat16* Ws1sb = (__hip_bfloat16*)alloc((size_t)512  * 544 * 2);
  __hip_bfloat16* Ws2b  = (__hip_bfloat16*)alloc((size_t)256  * 512 * 2);
  __hip_bfloat16* big   = (__hip_bfloat16*)alloc((size_t)Nt * 544 * 2);  // h1 / g1 / z
  __hip_bfloat16* z2b   = (__hip_bfloat16*)alloc((size_t)Ns * 256 * 2);

  init_meta_kernel<<<dim3(128), dim3(256), 0, stream>>>(map_s, map_t, cnt, iacc, cacc, Ns, Nt);
  {
    int n = Ns > Nt ? Ns : Nt;
    build_maps_kernel<<<dim3((n + 255) / 256), dim3(256), 0, stream>>>(
        sics, Ns, tics, Nt, map_s, map_t, cnt);
  }
  auto conv = [&](const float* src, int sld, __hip_bfloat16* dst, int rows, int K, int Kpad) {
    int total = rows * Kpad;
    convert_pad_kernel<<<dim3((total + 255) / 256), dim3(256), 0, stream>>>(
        src, sld, dst, total, K, Kpad);
  };
  conv(Wi1, 528,  Wi1b,  528,  528, 544);
  conv(Wi2, 528,  Wi2b,  1024, 528, 544);
  conv(Wc1, 528,  Wc1b,  528,  528, 544);
  conv(Wc2, 528,  Wc2b,  1024, 528, 544);
  conv(Ws1, 2576, Ws1sb, 512,  528, 544);
  conv(Ws2, 512,  Ws2b,  256,  512, 512);

  // GEMM1: h1 = relu(geo_src @ Wi1^T + bi1) -> big (ld 544)
  gemm_kernel<1, 0><<<dim3(Ns / 128, 5), dim3(256), 0, stream>>>(
      geo, D, Wi1b, 544, bi1, nullptr, nullptr, nullptr, big, 544, Ns, 528, 528, 544);
  // GEMM2: inst_acc[b] += sum relu(h1 @ Wi2^T + bi2)
  gemm_kernel<0, 1><<<dim3(Ns / 128, 8), dim3(256), 0, stream>>>(
      big, 544, Wi2b, 544, bi2, iacc, nullptr, sics, nullptr, 0, Ns, 1024, 528, 544);
  // GEMM3: g1 = relu(geo_tgt @ Wc1^T + bc1) -> big
  gemm_kernel<1, 0><<<dim3(Nt / 128, 5), dim3(256), 0, stream>>>(
      geo + (size_t)Ns * D, D, Wc1b, 544, bc1, nullptr, nullptr, nullptr, big, 544, Nt, 528, 528, 544);
  // GEMM4: cat_acc[b] += sum relu(g1 @ Wc2^T + bc2)
  gemm_kernel<0, 1><<<dim3(Nt / 128, 8), dim3(256), 0, stream>>>(
      big, 544, Wc2b, 544, bc2, cacc, nullptr, tics, nullptr, 0, Nt, 1024, 528, 544);

  glob_kernel<<<dim3(1024), dim3(256), 0, stream>>>(iacc, cacc, cnt, Ws1, bs1, globb);
  s_empty_kernel<<<dim3(8), dim3(256), 0, stream>>>(globb, Ws2, bs2, Ws3, bs3, semp);

  // GEMM5: z = relu(geo_src @ Ws1_s^T + glob[b]) -> big (ld 512)
  gemm_kernel<1, 2><<<dim3(Ns / 128, 4), dim3(256), 0, stream>>>(
      geo, D, Ws1sb, 544, nullptr, nullptr, globb, sics, big, 512, Ns, 512, 528, 544);
  // GEMM6: z2 = relu(z @ Ws2^T + bs2) -> z2b (ld 256)
  gemm_kernel<0, 0><<<dim3(Ns / 128, 2), dim3(256), 0, stream>>>(
      big, 512, Ws2b, 512, bs2, nullptr, nullptr, nullptr, z2b, 256, Ns, 256, 512, 512);

  s_dot_kernel<<<dim3((Ns + 3) / 4), dim3(256), 0, stream>>>(z2b, Ws3, bs3, sbuf, Ns);

  float inv = 1.0f / sqrtf(528.0f);
  fill_feats_kernel<<<dim3(65536), dim3(256), 0, stream>>>(geo, map_s, map_t, out0, out1, Ns, inv);
  fill_pcd_kernel<<<dim3(256), dim3(256), 0, stream>>>(pcd, map_s, map_t, out2, out3, Ns);
  scale_kernel<<<dim3(128), dim3(256), 0, stream>>>(sbuf, semp, map_s, out4);
}

// Round 3
// 581.807 us; speedup vs baseline: 2.0488x; 1.1059x over previous
//
#include <hip/hip_runtime.h>
#include <hip/hip_bf16.h>
#include <cstdint>
#include <cstddef>

typedef float f32x4 __attribute__((ext_vector_type(4)));
typedef __bf16 bf16x8v __attribute__((ext_vector_type(8)));

#define BM 128
#define BN 128
#define BK 32

// async global->LDS, 16 B per lane
__device__ __forceinline__ void gld16(const void* g, void* l) {
  __builtin_amdgcn_global_load_lds((const __attribute__((address_space(1))) void*)g,
                                   (__attribute__((address_space(3))) void*)l, 16, 0, 0);
}

// ---------------- small kernels ----------------
// cnt layout: cnt[0..8] = src batch start offsets (cnt[8]=Ns), cnt[9..17] = tgt starts (cnt[17]=Nt)

__global__ void build_maps_kernel(const int* __restrict__ sics, int Ns,
                                  const int* __restrict__ tics, int Nt,
                                  int* __restrict__ cnt) {
  int j = blockIdx.x * 256 + threadIdx.x;
  if (j < Ns) {
    if (j == 0) { cnt[0] = 0; cnt[8] = Ns; }
    else { int b = sics[j] >> 12; if ((sics[j - 1] >> 12) != b) cnt[b] = j; }
  }
  if (j < Nt) {
    if (j == 0) { cnt[9] = 0; cnt[17] = Nt; }
    else { int b = tics[j] >> 12; if ((tics[j - 1] >> 12) != b) cnt[9 + b] = j; }
  }
}

struct PrepParams {
  const float* src[6];
  __hip_bfloat16* dst[6];
  int sld[6], rows[6], K[6], Kpad[6], rows_pad[6];
  float* zbuf; int ztotal;
};

// one launch: 6 weight conversions (fp32 -> bf16, zero-padded in K and N) + acc zeroing
__global__ void prep_kernel(PrepParams P) {
  int job = blockIdx.y;
  int i = blockIdx.x * 256 + threadIdx.x;
  if (job == 6) {
    if (i < P.ztotal) P.zbuf[i] = 0.f;
    return;
  }
  int kp = P.Kpad[job];
  int total = P.rows_pad[job] * kp;
  if (i >= total) return;
  int r = i / kp;
  int k = i - r * kp;
  float v = (r < P.rows[job] && k < P.K[job]) ? P.src[job][(size_t)r * P.sld[job] + k] : 0.f;
  P.dst[job][i] = __float2bfloat16(v);
}

// ---------------- GEMM: C = relu(A @ W^T + bias-ish), bf16 MFMA ----------------
// EPI: 0 = bias+relu -> store bf16 to outp (cols [N,storepad) zeroed)
//      1 = bias+relu -> per-batch column sums atomically added to red_acc[b*N+col]
//      2 = glob[b][col]+relu -> store bf16
// M multiple of 128. All staging via global_load_lds (no predication: A is
// K-padded bf16, B is zero-padded to rows_pad >= n0+128).
template<int EPI>
__global__ __launch_bounds__(256, 2)
void gemm_kernel(const __hip_bfloat16* __restrict__ Aptr, int lda,
                 const __hip_bfloat16* __restrict__ Bw, int ldb,
                 const float* __restrict__ bias,
                 float* __restrict__ red_acc,
                 const float* __restrict__ globv,
                 const int* __restrict__ ridx,
                 __hip_bfloat16* __restrict__ outp, int ldo,
                 int M, int N, int Kpad, int storepad)
{
  __shared__ alignas(16) __hip_bfloat16 lA[BM * BK];
  __shared__ alignas(16) __hip_bfloat16 lB[BN * BK];
  const int tid  = threadIdx.x;
  const int lane = tid & 63;
  const int wave = tid >> 6;
  const int quad = lane >> 4;
  const int l16  = lane & 15;
  const int wr   = wave >> 1;
  const int wc   = wave & 1;
  const int m0   = blockIdx.x * BM;
  const int n0   = blockIdx.y * BN;

  // staging source pointers: chunk g in [0,512): row g>>2, k-chunk (g&3)*8
  const int srow = tid >> 2;
  const int skel = (tid & 3) << 3;
  const __hip_bfloat16* a0 = Aptr + (size_t)(m0 + srow) * lda + skel;
  const __hip_bfloat16* a1 = Aptr + (size_t)(m0 + 64 + srow) * lda + skel;
  const __hip_bfloat16* b0 = Bw + (size_t)(n0 + srow) * ldb + skel;
  const __hip_bfloat16* b1 = Bw + (size_t)(n0 + 64 + srow) * ldb + skel;
  __hip_bfloat16* lA0 = &lA[tid * 8];
  __hip_bfloat16* lA1 = &lA[2048 + tid * 8];
  __hip_bfloat16* lB0 = &lB[tid * 8];
  __hip_bfloat16* lB1 = &lB[2048 + tid * 8];

  f32x4 acc[4][4];
  const f32x4 zero4 = {0.f, 0.f, 0.f, 0.f};
#pragma unroll
  for (int i = 0; i < 4; ++i)
#pragma unroll
    for (int j = 0; j < 4; ++j) acc[i][j] = zero4;

  for (int k0 = 0; k0 < Kpad; k0 += BK) {
    gld16(a0 + k0, lA0);
    gld16(a1 + k0, lA1);
    gld16(b0 + k0, lB0);
    gld16(b1 + k0, lB1);
    __syncthreads();   // drains vmcnt -> LDS ready
    bf16x8v af[4], bfr[4];
#pragma unroll
    for (int i = 0; i < 4; ++i) {
      af[i]  = *(const bf16x8v*)&lA[(wr * 64 + i * 16 + l16) * BK + quad * 8];
      bfr[i] = *(const bf16x8v*)&lB[(wc * 64 + i * 16 + l16) * BK + quad * 8];
    }
#pragma unroll
    for (int mi = 0; mi < 4; ++mi)
#pragma unroll
      for (int ni = 0; ni < 4; ++ni)
        acc[mi][ni] = __builtin_amdgcn_mfma_f32_16x16x32_bf16(af[mi], bfr[ni], acc[mi][ni], 0, 0, 0);
    __syncthreads();   // readers done before next iter's writes
  }

  if (EPI == 1) {
    // masked per-batch column sums. Rows are batch-sorted; a 128-row tile spans
    // at most 2 batches (min batch len 2048).
    const int b0r = ridx[m0] >> 12;
#pragma unroll
    for (int ni = 0; ni < 4; ++ni) {
      const int col = n0 + wc * 64 + ni * 16 + l16;
      const bool colok = col < N;
      const float bcol = colok ? bias[col] : 0.f;
#pragma unroll
      for (int mi = 0; mi < 4; ++mi) {
        float v0 = 0.f, v1 = 0.f;
#pragma unroll
        for (int r = 0; r < 4; ++r) {
          const int row = m0 + wr * 64 + mi * 16 + quad * 4 + r;
          const float v = fmaxf(acc[mi][ni][r] + bcol, 0.f);
          const int b = ridx[row] >> 12;
          if (b == b0r) v0 += v; else v1 += v;
        }
        v0 += __shfl_xor(v0, 16, 64); v0 += __shfl_xor(v0, 32, 64);
        v1 += __shfl_xor(v1, 16, 64); v1 += __shfl_xor(v1, 32, 64);
        if (quad == 0 && colok) {
          atomicAdd(&red_acc[b0r * N + col], v0);
          if (b0r + 1 < 8 && v1 != 0.f) atomicAdd(&red_acc[(b0r + 1) * N + col], v1);
        }
      }
    }
  } else {
#pragma unroll
    for (int mi = 0; mi < 4; ++mi) {
#pragma unroll
      for (int r = 0; r < 4; ++r) {
        const int row = m0 + wr * 64 + mi * 16 + quad * 4 + r;
        int b = 0;
        if (EPI == 2) b = ridx[row] >> 12;
#pragma unroll
        for (int ni = 0; ni < 4; ++ni) {
          const int col = n0 + wc * 64 + ni * 16 + l16;
          if (col < N) {
            float v = acc[mi][ni][r];
            v += (EPI == 2) ? globv[b * N + col] : bias[col];
            v = fmaxf(v, 0.f);
            outp[(size_t)row * ldo + col] = __float2bfloat16(v);
          } else if (col < storepad) {
            outp[(size_t)row * ldo + col] = __float2bfloat16(0.f);  // K-pad for next GEMM
          }
        }
      }
    }
  }
}

// glob[b][o] = bs1[o] + (inst_acc[b]/ns) . Ws1[o,528:1552] + (cat_acc[b]/nt) . Ws1[o,1552:2576]
__global__ __launch_bounds__(256) void glob_kernel(const float* __restrict__ iacc,
                                                   const float* __restrict__ cacc,
                                                   const int* __restrict__ cnt,
                                                   const float* __restrict__ Ws1,
                                                   const float* __restrict__ bs1,
                                                   float* __restrict__ globv) {
  int w    = (blockIdx.x * 256 + threadIdx.x) >> 6;  // 4096 waves
  int lane = threadIdx.x & 63;
  int b = w >> 9;
  int o = w & 511;
  const float* wi  = Ws1 + (size_t)o * 2576 + 528;
  const float* wcp = Ws1 + (size_t)o * 2576 + 1552;
  float a1 = 0.f, a2 = 0.f;
  for (int k = lane; k < 1024; k += 64) {
    a1 += iacc[b * 1024 + k] * wi[k];
    a2 += cacc[b * 1024 + k] * wcp[k];
  }
  for (int off = 32; off; off >>= 1) {
    a1 += __shfl_xor(a1, off, 64);
    a2 += __shfl_xor(a2, off, 64);
  }
  if (lane == 0) {
    float ns = (float)(cnt[b + 1] - cnt[b]);
    float nt = (float)(cnt[9 + b + 1] - cnt[9 + b]);
    globv[b * 512 + o] = bs1[o] + a1 / ns + a2 / nt;
  }
}

// s value for an all-zero (invalid) row of batch b, full fp32 path
__global__ __launch_bounds__(256) void s_empty_kernel(const float* __restrict__ globv,
                                                      const float* __restrict__ Ws2,
                                                      const float* __restrict__ bs2,
                                                      const float* __restrict__ Ws3,
                                                      const float* __restrict__ bs3,
                                                      float* __restrict__ semp) {
  __shared__ float zrow[512];
  __shared__ float wsum[4];
  int b = blockIdx.x, t = threadIdx.x;
  zrow[t]       = fmaxf(globv[b * 512 + t], 0.f);
  zrow[t + 256] = fmaxf(globv[b * 512 + t + 256], 0.f);
  __syncthreads();
  float acc = bs2[t];
  for (int o = 0; o < 512; ++o) acc += zrow[o] * Ws2[t * 512 + o];
  float p = fmaxf(acc, 0.f) * Ws3[t];
  for (int off = 32; off; off >>= 1) p += __shfl_xor(p, off, 64);
  if ((t & 63) == 0) wsum[t >> 6] = p;
  __syncthreads();
  if (t == 0) semp[b] = wsum[0] + wsum[1] + wsum[2] + wsum[3] + bs3[0];
}

// s[row] = z2[row] . Ws3 + bs3 (one wave per row)
__global__ __launch_bounds__(256) void s_dot_kernel(const __hip_bfloat16* __restrict__ z2,
                                                    const float* __restrict__ Ws3,
                                                    const float* __restrict__ bs3,
                                                    float* __restrict__ sbuf, int M) {
  int w = (blockIdx.x * 256 + threadIdx.x) >> 6;
  int lane = threadIdx.x & 63;
  if (w >= M) return;
  const __hip_bfloat16* zr = z2 + (size_t)w * 256;
  float a = 0.f;
  for (int k = lane; k < 256; k += 64) a += __bfloat162float(zr[k]) * Ws3[k];
  for (int off = 32; off; off >>= 1) a += __shfl_xor(a, off, 64);
  if (lane == 0) sbuf[w] = a + bs3[0];
}

// outputs 0/1/2/3 + geo_b (bf16, K-padded to 544). One block per (side,pos) row.
__global__ __launch_bounds__(128)
void fill_feats_kernel(const float* __restrict__ geo, const float* __restrict__ pcd,
                       const int* __restrict__ cnt,
                       float* __restrict__ out0, float* __restrict__ out1,
                       float* __restrict__ out2, float* __restrict__ out3,
                       __hip_bfloat16* __restrict__ geo_b, int Ns, float inv) {
  int bid = blockIdx.x;              // 0..65535
  bool is_t = bid >= 32768;
  int pos = is_t ? bid - 32768 : bid;
  int b = pos >> 12, r = pos & 4095;
  int base = is_t ? cnt[9 + b] : cnt[b];
  int lim  = (is_t ? cnt[9 + b + 1] : cnt[b + 1]) - base;
  int t = threadIdx.x;
  float* op = (is_t ? out1 : out0) + (size_t)pos * 528;
  float* pp = (is_t ? out3 : out2) + (size_t)pos * 3;
  if (r < lim) {
    int src_row = (is_t ? Ns : 0) + base + r;
    const float4* g = (const float4*)(geo + (size_t)src_row * 528);
    ushort4* gb = (ushort4*)(geo_b + (size_t)src_row * 544);
    for (int d = t; d < 136; d += 128) {
      if (d < 132) {
        float4 v = g[d];
        float4 s; s.x = v.x * inv; s.y = v.y * inv; s.z = v.z * inv; s.w = v.w * inv;
        ((float4*)op)[d] = s;
        __hip_bfloat16 h0 = __float2bfloat16(v.x), h1 = __float2bfloat16(v.y);
        __hip_bfloat16 h2 = __float2bfloat16(v.z), h3 = __float2bfloat16(v.w);
        ushort4 u;
        u.x = *(unsigned short*)&h0; u.y = *(unsigned short*)&h1;
        u.z = *(unsigned short*)&h2; u.w = *(unsigned short*)&h3;
        gb[d] = u;
      } else {
        ushort4 u = {0, 0, 0, 0};
        gb[d] = u;                   // K-pad cols 528..543
      }
    }
    if (t < 3) pp[t] = pcd[(size_t)src_row * 3 + t];
  } else {
    float4 z = {0.f, 0.f, 0.f, 0.f};
    for (int d = t; d < 132; d += 128) ((float4*)op)[d] = z;
    if (t < 3) pp[t] = 0.f;
  }
}

__global__ void scale_kernel(const float* __restrict__ sbuf,
                             const float* __restrict__ semp,
                             const int* __restrict__ cnt,
                             float* __restrict__ out4) {
  int i = blockIdx.x * 256 + threadIdx.x;   // 0..32767
  if (i >= 32768) return;
  int b = i >> 12, r = i & 4095;
  int base = cnt[b];
  int lim = cnt[b + 1] - base;
  float s = (r < lim) ? sbuf[base + r] : semp[b];
  out4[i] = 1.f / (1.f + expf(-s)) - 0.5f;
}

// ---------------- host ----------------

extern "C" void kernel_launch(void* const* d_in, const int* in_sizes, int n_in,
                              void* d_out, int out_size, void* d_ws, size_t ws_size,
                              hipStream_t stream) {
  const float* geo = (const float*)d_in[0];
  const float* pcd = (const float*)d_in[1];
  const float* Wi1 = (const float*)d_in[2];
  const float* bi1 = (const float*)d_in[3];
  const float* Wi2 = (const float*)d_in[4];
  const float* bi2 = (const float*)d_in[5];
  const float* Wc1 = (const float*)d_in[6];
  const float* bc1 = (const float*)d_in[7];
  const float* Wc2 = (const float*)d_in[8];
  const float* bc2 = (const float*)d_in[9];
  const float* Ws1 = (const float*)d_in[10];
  const float* bs1 = (const float*)d_in[11];
  const float* Ws2 = (const float*)d_in[12];
  const float* bs2 = (const float*)d_in[13];
  const float* Ws3 = (const float*)d_in[14];
  const float* bs3 = (const float*)d_in[15];
  const int* sics = (const int*)d_in[18];
  const int* tics = (const int*)d_in[19];
  const int Ns = in_sizes[18];   // 23552 = 184*128
  const int Nt = in_sizes[19];   // 24704 = 193*128

  float* out0 = (float*)d_out;                      // (8,4096,528)
  float* out1 = out0 + (size_t)8 * 4096 * 528;      // (8,4096,528)
  float* out2 = out1 + (size_t)8 * 4096 * 528;      // (8,4096,3)
  float* out3 = out2 + (size_t)8 * 4096 * 3;        // (8,4096,3)
  float* out4 = out3 + (size_t)8 * 4096 * 3;        // (8,1,4096)

  char* wp = (char*)d_ws;
  auto alloc = [&](size_t bytes) -> void* {
    void* p = (void*)wp;
    wp += (bytes + 255) & ~(size_t)255;
    return p;
  };
  int*   cnt   = (int*)  alloc(128);
  float* iacc  = (float*)alloc((size_t)8 * 1024 * 4);   // contiguous with cacc
  float* cacc  = (float*)alloc((size_t)8 * 1024 * 4);
  float* globb = (float*)alloc((size_t)8 * 512 * 4);
  float* semp  = (float*)alloc(64);
  float* sbuf  = (float*)alloc((size_t)Ns * 4);
  __hip_bfloat16* Wi1b  = (__hip_bfloat16*)alloc((size_t)640  * 544 * 2);
  __hip_bfloat16* Wi2b  = (__hip_bfloat16*)alloc((size_t)1024 * 544 * 2);
  __hip_bfloat16* Wc1b  = (__hip_bfloat16*)alloc((size_t)640  * 544 * 2);
  __hip_bfloat16* Wc2b  = (__hip_bfloat16*)alloc((size_t)1024 * 544 * 2);
  __hip_bfloat16* Ws1sb = (__hip_bfloat16*)alloc((size_t)512  * 544 * 2);
  __hip_bfloat16* Ws2b  = (__hip_bfloat16*)alloc((size_t)256  * 512 * 2);
  __hip_bfloat16* geo_b = (__hip_bfloat16*)alloc((size_t)(Ns + Nt) * 544 * 2);
  __hip_bfloat16* big   = (__hip_bfloat16*)alloc((size_t)Nt * 544 * 2);  // h1 / g1 / z
  __hip_bfloat16* z2b   = (__hip_bfloat16*)alloc((size_t)Ns * 256 * 2);

  {
    int n = Ns > Nt ? Ns : Nt;
    build_maps_kernel<<<dim3((n + 255) / 256), dim3(256), 0, stream>>>(sics, Ns, tics, Nt, cnt);
  }
  {
    PrepParams P;
    const float* srcs[6]     = {Wi1, Wi2, Wc1, Wc2, Ws1, Ws2};
    __hip_bfloat16* dsts[6]  = {Wi1b, Wi2b, Wc1b, Wc2b, Ws1sb, Ws2b};
    int slds[6] = {528, 528, 528, 528, 2576, 512};
    int rows[6] = {528, 1024, 528, 1024, 512, 256};
    int Ks[6]   = {528, 528, 528, 528, 528, 512};
    int Kps[6]  = {544, 544, 544, 544, 544, 512};
    int rps[6]  = {640, 1024, 640, 1024, 512, 256};
    for (int i = 0; i < 6; ++i) {
      P.src[i] = srcs[i]; P.dst[i] = dsts[i]; P.sld[i] = slds[i];
      P.rows[i] = rows[i]; P.K[i] = Ks[i]; P.Kpad[i] = Kps[i]; P.rows_pad[i] = rps[i];
    }
    P.zbuf = iacc; P.ztotal = 16384;  // iacc+cacc contiguous
    prep_kernel<<<dim3(2176, 7), dim3(256), 0, stream>>>(P);
  }

  float inv = 1.0f / sqrtf(528.0f);
  fill_feats_kernel<<<dim3(65536), dim3(128), 0, stream>>>(
      geo, pcd, cnt, out0, out1, out2, out3, geo_b, Ns, inv);

  // GEMM1: h1 = relu(geo_src @ Wi1^T + bi1) -> big (ld 544, K-pad zeroed)
  gemm_kernel<0><<<dim3(Ns / 128, 5), dim3(256), 0, stream>>>(
      geo_b, 544, Wi1b, 544, bi1, nullptr, nullptr, nullptr, big, 544, Ns, 528, 544, 544);
  // GEMM2: inst_acc[b] += sum relu(h1 @ Wi2^T + bi2)
  gemm_kernel<1><<<dim3(Ns / 128, 8), dim3(256), 0, stream>>>(
      big, 544, Wi2b, 544, bi2, iacc, nullptr, sics, nullptr, 0, Ns, 1024, 544, 0);
  // GEMM3: g1 = relu(geo_tgt @ Wc1^T + bc1) -> big
  gemm_kernel<0><<<dim3(Nt / 128, 5), dim3(256), 0, stream>>>(
      geo_b + (size_t)Ns * 544, 544, Wc1b, 544, bc1, nullptr, nullptr, nullptr, big, 544, Nt, 528, 544, 544);
  // GEMM4: cat_acc[b] += sum relu(g1 @ Wc2^T + bc2)
  gemm_kernel<1><<<dim3(Nt / 128, 8), dim3(256), 0, stream>>>(
      big, 544, Wc2b, 544, bc2, cacc, nullptr, tics, nullptr, 0, Nt, 1024, 544, 0);

  glob_kernel<<<dim3(1024), dim3(256), 0, stream>>>(iacc, cacc, cnt, Ws1, bs1, globb);
  s_empty_kernel<<<dim3(8), dim3(256), 0, stream>>>(globb, Ws2, bs2, Ws3, bs3, semp);

  // GEMM5: z = relu(geo_src @ Ws1_s^T + glob[b]) -> big (ld 512)
  gemm_kernel<2><<<dim3(Ns / 128, 4), dim3(256), 0, stream>>>(
      geo_b, 544, Ws1sb, 544, nullptr, nullptr, globb, sics, big, 512, Ns, 512, 544, 512);
  // GEMM6: z2 = relu(z @ Ws2^T + bs2) -> z2b (ld 256)
  gemm_kernel<0><<<dim3(Ns / 128, 2), dim3(256), 0, stream>>>(
      big, 512, Ws2b, 512, bs2, nullptr, nullptr, nullptr, z2b, 256, Ns, 256, 512, 256);

  s_dot_kernel<<<dim3((Ns + 3) / 4), dim3(256), 0, stream>>>(z2b, Ws3, bs3, sbuf, Ns);
  scale_kernel<<<dim3(128), dim3(256), 0, stream>>>(sbuf, semp, cnt, out4);
}

// Round 4
// 516.962 us; speedup vs baseline: 2.3058x; 1.1254x over previous
//
#include <hip/hip_runtime.h>
#include <hip/hip_bf16.h>
#include <cstdint>
#include <cstddef>

typedef float f32x4 __attribute__((ext_vector_type(4)));
typedef __bf16 bf16x8v __attribute__((ext_vector_type(8)));
typedef __hip_bfloat16 bf16;

// async global->LDS, 16 B per lane (lds ptr: wave-uniform base + lane*16)
__device__ __forceinline__ void gld16(const void* g, void* l) {
  __builtin_amdgcn_global_load_lds((const __attribute__((address_space(1))) void*)g,
                                   (__attribute__((address_space(3))) void*)l, 16, 0, 0);
}

// ---------------- prep: weights->bf16(Kpad), zero accs, geo->bf16(ld576), batch offsets ----
// cnt layout: cnt[0..8] = src batch start offsets (cnt[8]=Ns), cnt[9..17] = tgt starts

struct PrepP {
  const float* Wsrc[6];
  bf16* Wdst[6];
  int sld[6], rows[6], K[6], Kpad[6];
  int off[10];            // block-range starts: jobs 0..5 weights, 6 zero, 7 geo_b, 8 maps; off[9]=end
  float* zbuf; int ztotal;
  const float* geo; bf16* geo_b; int Nrows;
  const int* sics; const int* tics; int Ns, Nt; int* cnt;
};

__global__ void prep_kernel(PrepP P) {
  int blk = blockIdx.x;
  int job = 0;
  while (job < 8 && blk >= P.off[job + 1]) ++job;
  int local = blk - P.off[job];
  if (job < 6) {
    int i = local * 256 + threadIdx.x;
    int kp = P.Kpad[job];
    int total = P.rows[job] * kp;
    if (i < total) {
      int r = i / kp, k = i - r * kp;
      float v = (k < P.K[job]) ? P.Wsrc[job][(size_t)r * P.sld[job] + k] : 0.f;
      P.Wdst[job][i] = __float2bfloat16(v);
    }
  } else if (job == 6) {
    int i = local * 256 + threadIdx.x;
    if (i < P.ztotal) P.zbuf[i] = 0.f;
  } else if (job == 7) {
    int t = local * 256 + threadIdx.x;
    int row = t / 72, c8 = t - row * 72;
    if (row < P.Nrows) {
      int col = c8 * 8;
      bf16* dst = P.geo_b + (size_t)row * 576 + col;
      if (c8 < 66) {
        const float* s = P.geo + (size_t)row * 528 + col;
        float4 f0 = ((const float4*)s)[0], f1 = ((const float4*)s)[1];
        bf16 h[8] = {__float2bfloat16(f0.x), __float2bfloat16(f0.y),
                     __float2bfloat16(f0.z), __float2bfloat16(f0.w),
                     __float2bfloat16(f1.x), __float2bfloat16(f1.y),
                     __float2bfloat16(f1.z), __float2bfloat16(f1.w)};
        ((uint4*)dst)[0] = *(uint4*)h;
      } else {
        uint4 z = {0u, 0u, 0u, 0u};
        ((uint4*)dst)[0] = z;      // K-pad cols 528..575
      }
    }
  } else {  // maps: batch start offsets, atomic-free
    int j = local * 256 + threadIdx.x;
    if (j < P.Ns) {
      if (j == 0) { P.cnt[0] = 0; P.cnt[8] = P.Ns; }
      else { int b = P.sics[j] >> 12; if ((P.sics[j - 1] >> 12) != b) P.cnt[b] = j; }
    }
    if (j < P.Nt) {
      if (j == 0) { P.cnt[9] = 0; P.cnt[17] = P.Nt; }
      else { int b = P.tics[j] >> 12; if ((P.tics[j - 1] >> 12) != b) P.cnt[9 + b] = j; }
    }
  }
}

// ---------------- GEMM core: 128x128 tile, BK=64 via twin 128x32 LDS buffers ----------------
// 8 outstanding global_load_lds, 32 MFMA per barrier pair.
__device__ __forceinline__ void gemm_core(
    const bf16* __restrict__ Aptr, int lda,
    const bf16* __restrict__ Bw, int ldb,
    int m0, int n0, int kiters,
    bf16* __restrict__ lA, bf16* __restrict__ lB,
    f32x4 acc[4][4])
{
  const int tid  = threadIdx.x;
  const int lane = tid & 63;
  const int quad = lane >> 4;
  const int l16  = lane & 15;
  const int wr   = tid >> 7;
  const int wc   = (tid >> 6) & 1;
  const int srow = tid >> 2;
  const int scol = (tid & 3) << 3;
  const bf16* aA0 = Aptr + (size_t)(m0 + srow) * lda + scol;
  const bf16* aA1 = aA0 + (size_t)64 * lda;
  const bf16* aB0 = Bw + (size_t)(n0 + srow) * ldb + scol;
  const bf16* aB1 = aB0 + (size_t)64 * ldb;
  bf16* lA00 = lA + tid * 8;        bf16* lA01 = lA + 2048 + tid * 8;
  bf16* lA10 = lA + 4096 + tid * 8; bf16* lA11 = lA + 6144 + tid * 8;
  bf16* lB00 = lB + tid * 8;        bf16* lB01 = lB + 2048 + tid * 8;
  bf16* lB10 = lB + 4096 + tid * 8; bf16* lB11 = lB + 6144 + tid * 8;

  for (int k = 0; k < kiters; ++k) {
    const int k0 = k * 64;
    gld16(aA0 + k0, lA00);      gld16(aA1 + k0, lA01);
    gld16(aA0 + k0 + 32, lA10); gld16(aA1 + k0 + 32, lA11);
    gld16(aB0 + k0, lB00);      gld16(aB1 + k0, lB01);
    gld16(aB0 + k0 + 32, lB10); gld16(aB1 + k0 + 32, lB11);
    __syncthreads();
#pragma unroll
    for (int kk = 0; kk < 2; ++kk) {
      bf16x8v af[4], bfr[4];
#pragma unroll
      for (int i = 0; i < 4; ++i) {
        af[i]  = *(const bf16x8v*)&lA[kk * 4096 + (wr * 64 + i * 16 + l16) * 32 + quad * 8];
        bfr[i] = *(const bf16x8v*)&lB[kk * 4096 + (wc * 64 + i * 16 + l16) * 32 + quad * 8];
      }
#pragma unroll
      for (int mi = 0; mi < 4; ++mi)
#pragma unroll
        for (int ni = 0; ni < 4; ++ni)
          acc[mi][ni] = __builtin_amdgcn_mfma_f32_16x16x32_bf16(af[mi], bfr[ni], acc[mi][ni], 0, 0, 0);
    }
    __syncthreads();
  }
}

// ---------------- kernel A: GEMM1 (src L1) + GEMM3 (tgt L1) + GEMM5-pre (z w/o glob) ------
__global__ __launch_bounds__(256, 2)
void kernelA(const bf16* __restrict__ geo_b,
             const bf16* __restrict__ Wi1b, const bf16* __restrict__ Wc1b,
             const bf16* __restrict__ Ws1sb,
             const float* __restrict__ bi1, const float* __restrict__ bc1,
             bf16* __restrict__ big_s, bf16* __restrict__ big_t,
             bf16* __restrict__ zpre, int Ms, int Mt)
{
  __shared__ alignas(16) bf16 lA[8192], lB[8192];
  const int x = blockIdx.x;
  const int e0 = Ms * 5, e1 = e0 + Mt * 5;
  const bf16 *A, *B; const float* bias = nullptr; bf16* out;
  int m0, n0, ldo, epi;
  if (x < e0) {
    int mt = x / 5, nt = x - mt * 5;
    m0 = mt * 128; n0 = nt * 128;
    A = geo_b; B = Wi1b; bias = bi1; out = big_s; ldo = 576; epi = 0;
  } else if (x < e1) {
    int y = x - e0; int mt = y / 5, nt = y - mt * 5;
    m0 = mt * 128; n0 = nt * 128;
    A = geo_b + (size_t)Ms * 128 * 576; B = Wc1b; bias = bc1; out = big_t; ldo = 576; epi = 0;
  } else {
    int y = x - e1; int mt = y / 4, nt = y - mt * 4;
    m0 = mt * 128; n0 = nt * 128;
    A = geo_b; B = Ws1sb; out = zpre; ldo = 512; epi = 1;
  }

  f32x4 acc[4][4];
  const f32x4 z4 = {0.f, 0.f, 0.f, 0.f};
#pragma unroll
  for (int i = 0; i < 4; ++i)
#pragma unroll
    for (int j = 0; j < 4; ++j) acc[i][j] = z4;

  gemm_core(A, 576, B, 576, m0, n0, 9, lA, lB, acc);

  const int lane = threadIdx.x & 63, quad = lane >> 4, l16 = lane & 15;
  const int wr = threadIdx.x >> 7, wc = (threadIdx.x >> 6) & 1;
#pragma unroll
  for (int mi = 0; mi < 4; ++mi) {
#pragma unroll
    for (int r = 0; r < 4; ++r) {
      const int row = m0 + wr * 64 + mi * 16 + quad * 4 + r;
#pragma unroll
      for (int ni = 0; ni < 4; ++ni) {
        const int col = n0 + wc * 64 + ni * 16 + l16;
        if (epi == 0) {
          if (col < 528)
            out[(size_t)row * ldo + col] = __float2bfloat16(fmaxf(acc[mi][ni][r] + bias[col], 0.f));
          else if (col < 576)
            out[(size_t)row * ldo + col] = __float2bfloat16(0.f);
        } else {
          out[(size_t)row * ldo + col] = __float2bfloat16(acc[mi][ni][r]);  // z_pre, raw
        }
      }
    }
  }
}

// ---------------- kernel B: GEMM2 + GEMM4 (batch-sum epilogue) + output fills ----------------
__global__ __launch_bounds__(256, 2)
void kernelB(const bf16* __restrict__ big_s, const bf16* __restrict__ big_t,
             const bf16* __restrict__ Wi2b, const bf16* __restrict__ Wc2b,
             const float* __restrict__ bi2, const float* __restrict__ bc2,
             float* __restrict__ iacc, float* __restrict__ cacc,
             const int* __restrict__ sics, const int* __restrict__ tics,
             int Ms, int Mt,
             const float* __restrict__ geo, const float* __restrict__ pcd,
             const int* __restrict__ cnt,
             float* __restrict__ out0, float* __restrict__ out1,
             float* __restrict__ out2, float* __restrict__ out3,
             int Ns, float inv)
{
  __shared__ alignas(16) bf16 lA[8192], lB[8192];
  const int x = blockIdx.x;
  const int e0 = Ms * 8, e1 = e0 + Mt * 8;
  if (x >= e1) {
    // -------- fill job: 4 output rows per block, 64 lanes/row --------
    int f = x - e1;
    int lane = threadIdx.x & 63;
    int rv = f * 4 + (threadIdx.x >> 6);       // 0..65535
    bool is_t = rv >= 32768;
    int pos = is_t ? rv - 32768 : rv;
    int b = pos >> 12, r = pos & 4095;
    int base = is_t ? cnt[9 + b] : cnt[b];
    int lim  = (is_t ? cnt[9 + b + 1] : cnt[b + 1]) - base;
    float* op = (is_t ? out1 : out0) + (size_t)pos * 528;
    float* pp = (is_t ? out3 : out2) + (size_t)pos * 3;
    if (r < lim) {
      int sr = (is_t ? Ns : 0) + base + r;
      const float4* g = (const float4*)(geo + (size_t)sr * 528);
      for (int d = lane; d < 132; d += 64) {
        float4 v = g[d];
        float4 s = {v.x * inv, v.y * inv, v.z * inv, v.w * inv};
        ((float4*)op)[d] = s;
      }
      if (lane < 3) pp[lane] = pcd[(size_t)sr * 3 + lane];
    } else {
      float4 z = {0.f, 0.f, 0.f, 0.f};
      for (int d = lane; d < 132; d += 64) ((float4*)op)[d] = z;
      if (lane < 3) pp[lane] = 0.f;
    }
    return;
  }
  // -------- GEMM job --------
  const bf16 *A, *B; const float* bias; float* red; const int* ridx;
  int m0, n0;
  if (x < e0) {
    int mt = x / 8, nt = x - mt * 8;
    m0 = mt * 128; n0 = nt * 128;
    A = big_s; B = Wi2b; bias = bi2; red = iacc; ridx = sics;
  } else {
    int y = x - e0; int mt = y / 8, nt = y - mt * 8;
    m0 = mt * 128; n0 = nt * 128;
    A = big_t; B = Wc2b; bias = bc2; red = cacc; ridx = tics;
  }

  f32x4 acc[4][4];
  const f32x4 z4 = {0.f, 0.f, 0.f, 0.f};
#pragma unroll
  for (int i = 0; i < 4; ++i)
#pragma unroll
    for (int j = 0; j < 4; ++j) acc[i][j] = z4;

  gemm_core(A, 576, B, 576, m0, n0, 9, lA, lB, acc);

  // per-batch column sums (rows batch-sorted; 128-row tile spans <=2 batches)
  const int lane = threadIdx.x & 63, quad = lane >> 4, l16 = lane & 15;
  const int wr = threadIdx.x >> 7, wc = (threadIdx.x >> 6) & 1;
  const int b0r = ridx[m0] >> 12;
#pragma unroll
  for (int ni = 0; ni < 4; ++ni) {
    const int col = n0 + wc * 64 + ni * 16 + l16;
    const float bcol = bias[col];
#pragma unroll
    for (int mi = 0; mi < 4; ++mi) {
      float v0 = 0.f, v1 = 0.f;
#pragma unroll
      for (int r = 0; r < 4; ++r) {
        const int row = m0 + wr * 64 + mi * 16 + quad * 4 + r;
        const float v = fmaxf(acc[mi][ni][r] + bcol, 0.f);
        const int b = ridx[row] >> 12;
        if (b == b0r) v0 += v; else v1 += v;
      }
      v0 += __shfl_xor(v0, 16, 64); v0 += __shfl_xor(v0, 32, 64);
      v1 += __shfl_xor(v1, 16, 64); v1 += __shfl_xor(v1, 32, 64);
      if (quad == 0) {
        atomicAdd(&red[b0r * 1024 + col], v0);
        if (b0r + 1 < 8 && v1 != 0.f) atomicAdd(&red[(b0r + 1) * 1024 + col], v1);
      }
    }
  }
}

// ---------------- kernel C: GEMM6 + fused s-dot (z2 never materialized) ----------------
__global__ __launch_bounds__(256, 2)
void kernelC(const bf16* __restrict__ zpre, const bf16* __restrict__ Ws2b,
             const float* __restrict__ bs2, const float* __restrict__ Ws3,
             float* __restrict__ sbuf)
{
  __shared__ alignas(16) bf16 lA[8192], lB[8192];
  const int m0 = blockIdx.x * 128, n0 = blockIdx.y * 128;
  f32x4 acc[4][4];
  const f32x4 z4 = {0.f, 0.f, 0.f, 0.f};
#pragma unroll
  for (int i = 0; i < 4; ++i)
#pragma unroll
    for (int j = 0; j < 4; ++j) acc[i][j] = z4;

  gemm_core(zpre, 512, Ws2b, 512, m0, n0, 8, lA, lB, acc);

  const int lane = threadIdx.x & 63, quad = lane >> 4, l16 = lane & 15;
  const int wr = threadIdx.x >> 7, wc = (threadIdx.x >> 6) & 1;
#pragma unroll
  for (int mi = 0; mi < 4; ++mi) {
#pragma unroll
    for (int r = 0; r < 4; ++r) {
      const int row = m0 + wr * 64 + mi * 16 + quad * 4 + r;
      float p = 0.f;
#pragma unroll
      for (int ni = 0; ni < 4; ++ni) {
        const int col = n0 + wc * 64 + ni * 16 + l16;
        p += fmaxf(acc[mi][ni][r] + bs2[col], 0.f) * Ws3[col];
      }
      p += __shfl_xor(p, 1, 64); p += __shfl_xor(p, 2, 64);
      p += __shfl_xor(p, 4, 64); p += __shfl_xor(p, 8, 64);
      if (l16 == 0) atomicAdd(&sbuf[row], p);
    }
  }
}

// glob[b][o] = bs1[o] + (iacc[b]/ns) . Ws1[o,528:1552] + (cacc[b]/nt) . Ws1[o,1552:2576]
__global__ __launch_bounds__(256) void glob_kernel(const float* __restrict__ iacc,
                                                   const float* __restrict__ cacc,
                                                   const int* __restrict__ cnt,
                                                   const float* __restrict__ Ws1,
                                                   const float* __restrict__ bs1,
                                                   float* __restrict__ globv) {
  int w    = (blockIdx.x * 256 + threadIdx.x) >> 6;  // 4096 waves
  int lane = threadIdx.x & 63;
  int b = w >> 9;
  int o = w & 511;
  const float* wi  = Ws1 + (size_t)o * 2576 + 528;
  const float* wcp = Ws1 + (size_t)o * 2576 + 1552;
  float a1 = 0.f, a2 = 0.f;
  for (int k = lane; k < 1024; k += 64) {
    a1 += iacc[b * 1024 + k] * wi[k];
    a2 += cacc[b * 1024 + k] * wcp[k];
  }
  for (int off = 32; off; off >>= 1) {
    a1 += __shfl_xor(a1, off, 64);
    a2 += __shfl_xor(a2, off, 64);
  }
  if (lane == 0) {
    float ns = (float)(cnt[b + 1] - cnt[b]);
    float nt = (float)(cnt[9 + b + 1] - cnt[9 + b]);
    globv[b * 512 + o] = bs1[o] + a1 / ns + a2 / nt;
  }
}

// s value for an all-zero (invalid) row of batch b, full fp32 path (includes bs3)
__global__ __launch_bounds__(256) void s_empty_kernel(const float* __restrict__ globv,
                                                      const float* __restrict__ Ws2,
                                                      const float* __restrict__ bs2,
                                                      const float* __restrict__ Ws3,
                                                      const float* __restrict__ bs3,
                                                      float* __restrict__ semp) {
  __shared__ float zrow[512];
  __shared__ float wsum[4];
  int b = blockIdx.x, t = threadIdx.x;
  zrow[t]       = fmaxf(globv[b * 512 + t], 0.f);
  zrow[t + 256] = fmaxf(globv[b * 512 + t + 256], 0.f);
  __syncthreads();
  float acc = bs2[t];
  for (int o = 0; o < 512; ++o) acc += zrow[o] * Ws2[t * 512 + o];
  float p = fmaxf(acc, 0.f) * Ws3[t];
  for (int off = 32; off; off >>= 1) p += __shfl_xor(p, off, 64);
  if ((t & 63) == 0) wsum[t >> 6] = p;
  __syncthreads();
  if (t == 0) semp[b] = wsum[0] + wsum[1] + wsum[2] + wsum[3] + bs3[0];
}

// z = relu(z_pre + glob[b]) in-place (bf16x8 chunks)
__global__ void zfix_kernel(bf16* __restrict__ z, const float* __restrict__ globv,
                            const int* __restrict__ sics, int total) {
  int idx = blockIdx.x * 256 + threadIdx.x;
  if (idx >= total) return;                      // total = Ns*64
  int row = idx >> 6, c0 = (idx & 63) << 3;
  int b = sics[row] >> 12;
  const float* gv = globv + b * 512 + c0;
  bf16* zp = z + (size_t)row * 512 + c0;
  uint4 u = *(uint4*)zp;
  bf16* e = (bf16*)&u;
#pragma unroll
  for (int i = 0; i < 8; ++i)
    e[i] = __float2bfloat16(fmaxf(__bfloat162float(e[i]) + gv[i], 0.f));
  *(uint4*)zp = u;
}

__global__ void scale_kernel(const float* __restrict__ sbuf,
                             const float* __restrict__ semp,
                             const int* __restrict__ cnt,
                             const float* __restrict__ bs3,
                             float* __restrict__ out4) {
  int i = blockIdx.x * 256 + threadIdx.x;   // 0..32767
  if (i >= 32768) return;
  int b = i >> 12, r = i & 4095;
  int base = cnt[b];
  int lim = cnt[b + 1] - base;
  float s = (r < lim) ? sbuf[base + r] + bs3[0] : semp[b];
  out4[i] = 1.f / (1.f + expf(-s)) - 0.5f;
}

// ---------------- host ----------------

extern "C" void kernel_launch(void* const* d_in, const int* in_sizes, int n_in,
                              void* d_out, int out_size, void* d_ws, size_t ws_size,
                              hipStream_t stream) {
  const float* geo = (const float*)d_in[0];
  const float* pcd = (const float*)d_in[1];
  const float* Wi1 = (const float*)d_in[2];
  const float* bi1 = (const float*)d_in[3];
  const float* Wi2 = (const float*)d_in[4];
  const float* bi2 = (const float*)d_in[5];
  const float* Wc1 = (const float*)d_in[6];
  const float* bc1 = (const float*)d_in[7];
  const float* Wc2 = (const float*)d_in[8];
  const float* bc2 = (const float*)d_in[9];
  const float* Ws1 = (const float*)d_in[10];
  const float* bs1 = (const float*)d_in[11];
  const float* Ws2 = (const float*)d_in[12];
  const float* bs2 = (const float*)d_in[13];
  const float* Ws3 = (const float*)d_in[14];
  const float* bs3 = (const float*)d_in[15];
  const int* sics = (const int*)d_in[18];
  const int* tics = (const int*)d_in[19];
  const int Ns = in_sizes[18];   // 23552 = 184*128
  const int Nt = in_sizes[19];   // 24704 = 193*128
  const int Ms = Ns / 128, Mt = Nt / 128;
  const int Nrows = Ns + Nt;

  float* out0 = (float*)d_out;                      // (8,4096,528)
  float* out1 = out0 + (size_t)8 * 4096 * 528;      // (8,4096,528)
  float* out2 = out1 + (size_t)8 * 4096 * 528;      // (8,4096,3)
  float* out3 = out2 + (size_t)8 * 4096 * 3;        // (8,4096,3)
  float* out4 = out3 + (size_t)8 * 4096 * 3;        // (8,1,4096)

  char* wp = (char*)d_ws;
  auto alloc = [&](size_t bytes) -> void* {
    void* p = (void*)wp;
    wp += (bytes + 255) & ~(size_t)255;
    return p;
  };
  int*   cnt   = (int*)  alloc(128);
  float* iacc  = (float*)alloc((size_t)8 * 1024 * 4);   // iacc/cacc/sbuf contiguous (zero job)
  float* cacc  = (float*)alloc((size_t)8 * 1024 * 4);
  float* sbuf  = (float*)alloc((size_t)Ns * 4);
  float* globb = (float*)alloc((size_t)8 * 512 * 4);
  float* semp  = (float*)alloc(64);
  bf16* Wi1b  = (bf16*)alloc((size_t)640  * 576 * 2);   // rows 528..639 uninit (cols discarded)
  bf16* Wi2b  = (bf16*)alloc((size_t)1024 * 576 * 2);
  bf16* Wc1b  = (bf16*)alloc((size_t)640  * 576 * 2);
  bf16* Wc2b  = (bf16*)alloc((size_t)1024 * 576 * 2);
  bf16* Ws1sb = (bf16*)alloc((size_t)512  * 576 * 2);
  bf16* Ws2b  = (bf16*)alloc((size_t)256  * 512 * 2);
  bf16* geo_b = (bf16*)alloc((size_t)Nrows * 576 * 2);
  bf16* big_s = (bf16*)alloc((size_t)Ns * 576 * 2);
  bf16* big_t = (bf16*)alloc((size_t)Nt * 576 * 2);
  bf16* zpre  = (bf16*)alloc((size_t)Ns * 512 * 2);

  // ---- prep ----
  PrepP P;
  {
    const float* srcs[6] = {Wi1, Wi2, Wc1, Wc2, Ws1, Ws2};
    bf16* dsts[6]        = {Wi1b, Wi2b, Wc1b, Wc2b, Ws1sb, Ws2b};
    int slds[6] = {528, 528, 528, 528, 2576, 512};
    int rows[6] = {528, 1024, 528, 1024, 512, 256};
    int Ks[6]   = {528, 528, 528, 528, 528, 512};
    int Kps[6]  = {576, 576, 576, 576, 576, 512};
    int nblk = 0;
    for (int i = 0; i < 6; ++i) {
      P.Wsrc[i] = srcs[i]; P.Wdst[i] = dsts[i]; P.sld[i] = slds[i];
      P.rows[i] = rows[i]; P.K[i] = Ks[i]; P.Kpad[i] = Kps[i];
      P.off[i] = nblk;
      nblk += (rows[i] * Kps[i] + 255) / 256;
    }
    P.off[6] = nblk;
    P.zbuf = iacc; P.ztotal = 8192 + 8192 + Ns;
    nblk += (P.ztotal + 255) / 256;
    P.off[7] = nblk;
    P.geo = geo; P.geo_b = geo_b; P.Nrows = Nrows;
    nblk += ((Nrows * 72) + 255) / 256;
    P.off[8] = nblk;
    P.sics = sics; P.tics = tics; P.Ns = Ns; P.Nt = Nt; P.cnt = cnt;
    int n = Ns > Nt ? Ns : Nt;
    nblk += (n + 255) / 256;
    P.off[9] = nblk;
    prep_kernel<<<dim3(nblk), dim3(256), 0, stream>>>(P);
  }

  // ---- kernel A: L1-src, L1-tgt, z_pre ----
  kernelA<<<dim3(Ms * 5 + Mt * 5 + Ms * 4), dim3(256), 0, stream>>>(
      geo_b, Wi1b, Wc1b, Ws1sb, bi1, bc1, big_s, big_t, zpre, Ms, Mt);

  // ---- kernel B: L2-src, L2-tgt (batch sums) + output fills ----
  float inv = 1.0f / sqrtf(528.0f);
  kernelB<<<dim3(Ms * 8 + Mt * 8 + 16384), dim3(256), 0, stream>>>(
      big_s, big_t, Wi2b, Wc2b, bi2, bc2, iacc, cacc, sics, tics, Ms, Mt,
      geo, pcd, cnt, out0, out1, out2, out3, Ns, inv);

  glob_kernel<<<dim3(1024), dim3(256), 0, stream>>>(iacc, cacc, cnt, Ws1, bs1, globb);
  s_empty_kernel<<<dim3(8), dim3(256), 0, stream>>>(globb, Ws2, bs2, Ws3, bs3, semp);
  zfix_kernel<<<dim3((Ns * 64 + 255) / 256), dim3(256), 0, stream>>>(zpre, globb, sics, Ns * 64);
  kernelC<<<dim3(Ms, 2), dim3(256), 0, stream>>>(zpre, Ws2b, bs2, Ws3, sbuf);
  scale_kernel<<<dim3(128), dim3(256), 0, stream>>>(sbuf, semp, cnt, bs3, out4);
}